// Round 1
// baseline (186.478 us; speedup 1.0000x reference)
//
#include <hip/hip_runtime.h>
#include <math.h>

// Problem constants (match reference)
#define B_ 2048
#define L_ 200
#define V_ 50000
#define D_ 300
#define H_ 128
#define C_ 20

// -----------------------------------------------------------------------------
// Kernel 1: per-batch-row embedding gather + sum/max reduction.
// One block (256 threads) per batch row. 225 active lanes: lane = (g, p),
// g in [0,3) picks which of 3 interleaved L-rows, p in [0,75) picks the
// float4 quad within the 300-float embedding row (75 quads * 16 B = 1200 B,
// 16-byte aligned since 300*4 = 1200 = 75*16).
// Writes rep[b][0:300] = sum/len^2 (reference's preserved bug), rep[b][300:600] = max.
// -----------------------------------------------------------------------------
__global__ __launch_bounds__(256, 4) void gather_reduce_kernel(
    const int* __restrict__ x,        // [B][L]
    const int* __restrict__ lengths,  // [B]
    const float* __restrict__ emb,    // [V][D]
    float* __restrict__ rep)          // [B][2D]
{
    __shared__ int s_idx[L_];
    __shared__ float4 s_sum[225];
    __shared__ float4 s_max[225];

    const int b = blockIdx.x;
    const int t = threadIdx.x;

    if (t < L_) s_idx[t] = x[b * L_ + t];
    __syncthreads();

    if (t < 225) {
        const int g = t / 75;       // 0..2
        const int p = t - g * 75;   // 0..74
        float4 s4 = make_float4(0.f, 0.f, 0.f, 0.f);
        float4 m4 = make_float4(-INFINITY, -INFINITY, -INFINITY, -INFINITY);
        #pragma unroll 4
        for (int l = g; l < L_; l += 3) {
            const float4 v =
                *(const float4*)(emb + (size_t)s_idx[l] * D_ + (p << 2));
            s4.x += v.x; s4.y += v.y; s4.z += v.z; s4.w += v.w;
            m4.x = fmaxf(m4.x, v.x); m4.y = fmaxf(m4.y, v.y);
            m4.z = fmaxf(m4.z, v.z); m4.w = fmaxf(m4.w, v.w);
        }
        s_sum[t] = s4;
        s_max[t] = m4;
    }
    __syncthreads();

    if (t < 75) {
        const float4 sa = s_sum[t], sb = s_sum[t + 75], sc = s_sum[t + 150];
        const float4 ma = s_max[t], mb = s_max[t + 75], mc = s_max[t + 150];
        const float lf = (float)lengths[b];
        const float inv = 1.0f / (lf * lf);   // reference bug: sum / len^2
        float4 S, M;
        S.x = (sa.x + sb.x + sc.x) * inv;
        S.y = (sa.y + sb.y + sc.y) * inv;
        S.z = (sa.z + sb.z + sc.z) * inv;
        S.w = (sa.w + sb.w + sc.w) * inv;
        M.x = fmaxf(fmaxf(ma.x, mb.x), mc.x);
        M.y = fmaxf(fmaxf(ma.y, mb.y), mc.y);
        M.z = fmaxf(fmaxf(ma.z, mb.z), mc.z);
        M.w = fmaxf(fmaxf(ma.w, mb.w), mc.w);
        float4* o = (float4*)(rep + (size_t)b * (2 * D_));
        o[t]      = S;   // mean_bug part, d = 4t..4t+3
        o[75 + t] = M;   // max part,      d = 4t..4t+3 (offset 300 floats)
    }
}

// -----------------------------------------------------------------------------
// Kernel 2: fused 2-layer MLP.  h = relu(rep @ W_new^T + b_new);
// out = h @ W3^T + b3.  Block handles 8 batch rows; thread computes a
// 2-row x 2-col register micro-tile of h (rows {2rp,2rp+1}, cols {cp,cp+64}).
// rep staged in LDS (reads are wave-broadcast b128 -> cheap); W_new streamed
// from global (L2-resident, each element read once per block).
// -----------------------------------------------------------------------------
__global__ __launch_bounds__(256, 4) void mlp_kernel(
    const float* __restrict__ rep,    // [B][2D]
    const float* __restrict__ W_new,  // [H][2D]
    const float* __restrict__ b_new,  // [H]
    const float* __restrict__ W3,     // [C][H]
    const float* __restrict__ b3,     // [C]
    float* __restrict__ out)          // [B][C]
{
    __shared__ float s_rep[8 * 2 * D_];      // 8 rows * 600 = 19.2 KB
    __shared__ float s_h[8][H_ + 4];         // padded

    const int t = threadIdx.x;
    const int row0 = blockIdx.x * 8;

    // Stage 8 rep rows (contiguous 4800 floats = 1200 float4), coalesced.
    {
        const float4* src = (const float4*)(rep + (size_t)row0 * (2 * D_));
        float4* dst = (float4*)s_rep;
        for (int i = t; i < 1200; i += 256) dst[i] = src[i];
    }
    __syncthreads();

    // ---- Layer 1: 2x2 micro-tile ----
    const int rp = (t >> 6) * 2;   // rows rp, rp+1  (0,2,4,6)
    const int cp = t & 63;         // cols cp, cp+64
    float a00 = 0.f, a01 = 0.f, a10 = 0.f, a11 = 0.f;

    const float4* w0 = (const float4*)(W_new + (size_t)cp * (2 * D_));
    const float4* w1 = (const float4*)(W_new + (size_t)(cp + 64) * (2 * D_));
    const float4* ra = (const float4*)(s_rep + rp * (2 * D_));
    const float4* rb = (const float4*)(s_rep + (rp + 1) * (2 * D_));

    #pragma unroll 5
    for (int q = 0; q < 150; ++q) {
        const float4 va = ra[q];
        const float4 vb = rb[q];
        const float4 wa = w0[q];
        const float4 wb = w1[q];
        a00 = fmaf(va.x, wa.x, a00); a00 = fmaf(va.y, wa.y, a00);
        a00 = fmaf(va.z, wa.z, a00); a00 = fmaf(va.w, wa.w, a00);
        a01 = fmaf(va.x, wb.x, a01); a01 = fmaf(va.y, wb.y, a01);
        a01 = fmaf(va.z, wb.z, a01); a01 = fmaf(va.w, wb.w, a01);
        a10 = fmaf(vb.x, wa.x, a10); a10 = fmaf(vb.y, wa.y, a10);
        a10 = fmaf(vb.z, wa.z, a10); a10 = fmaf(vb.w, wa.w, a10);
        a11 = fmaf(vb.x, wb.x, a11); a11 = fmaf(vb.y, wb.y, a11);
        a11 = fmaf(vb.z, wb.z, a11); a11 = fmaf(vb.w, wb.w, a11);
    }

    const float bn0 = b_new[cp];
    const float bn1 = b_new[cp + 64];
    s_h[rp    ][cp     ] = fmaxf(a00 + bn0, 0.f);
    s_h[rp    ][cp + 64] = fmaxf(a01 + bn1, 0.f);
    s_h[rp + 1][cp     ] = fmaxf(a10 + bn0, 0.f);
    s_h[rp + 1][cp + 64] = fmaxf(a11 + bn1, 0.f);
    __syncthreads();

    // ---- Layer 2: 8 rows x 20 classes = 160 outputs ----
    if (t < 8 * C_) {
        const int r = t / C_;
        const int c = t - r * C_;
        const float* hr = s_h[r];
        const float* w3 = W3 + c * H_;
        float acc = b3[c];
        #pragma unroll 8
        for (int k = 0; k < H_; ++k) acc = fmaf(hr[k], w3[k], acc);
        out[(size_t)(row0 + r) * C_ + c] = acc;
    }
}

// -----------------------------------------------------------------------------
extern "C" void kernel_launch(void* const* d_in, const int* in_sizes, int n_in,
                              void* d_out, int out_size, void* d_ws, size_t ws_size,
                              hipStream_t stream) {
    const int*   x       = (const int*)  d_in[0];
    const int*   lengths = (const int*)  d_in[1];
    const float* emb     = (const float*)d_in[2];
    const float* W_new   = (const float*)d_in[3];
    const float* b_new   = (const float*)d_in[4];
    const float* W3      = (const float*)d_in[5];
    const float* b3      = (const float*)d_in[6];
    float* out = (float*)d_out;
    float* rep = (float*)d_ws;   // [B][600] = 4.92 MB scratch

    gather_reduce_kernel<<<B_, 256, 0, stream>>>(x, lengths, emb, rep);
    mlp_kernel<<<B_ / 8, 256, 0, stream>>>(rep, W_new, b_new, W3, b3, out);
}